// Round 13
// baseline (164.525 us; speedup 1.0000x reference)
//
#include <hip/hip_runtime.h>

typedef _Float16 f16x8 __attribute__((ext_vector_type(8)));
typedef _Float16 f16x4 __attribute__((ext_vector_type(4)));
typedef float f32x4 __attribute__((ext_vector_type(4)));

#define EMB 768
#define LQ 128
#define LD 1024
#define NB 32

typedef const __attribute__((address_space(1))) char gas_char;
typedef __attribute__((address_space(3))) char las_char;

__device__ __forceinline__ void gload16(const void* g, void* l) {
    __builtin_amdgcn_global_load_lds((gas_char*)g, (las_char*)l, 16, 0, 0);
}

// 128B-row tiles: 8 chunks of 16B, XOR row&7. 0 bank conflicts measured (R7-R11).
#define SWZ(row, ch) ((row) * 64 + ((((ch) ^ ((row) & 7))) * 8))

#define BAR() asm volatile("s_barrier" ::: "memory")
#define LGKM0() do { asm volatile("s_waitcnt lgkmcnt(0)" ::: "memory"); \
                     __builtin_amdgcn_sched_barrier(0); } while (0)
#define VMW(N) asm volatile("s_waitcnt vmcnt(" #N ")" ::: "memory")
#define LGKM_FLUSH() asm volatile("s_waitcnt lgkmcnt(0)" ::: "memory")

// ---------- f32 -> f16, 8 elems/thread (W only) ----------
__global__ void cvt8_kernel(const float* __restrict__ in, _Float16* __restrict__ out, int n8) {
    int i = blockIdx.x * 256 + threadIdx.x;
    if (i >= n8) return;
    const float4 a = ((const float4*)in)[2 * i];
    const float4 b = ((const float4*)in)[2 * i + 1];
    f16x8 o;
    o[0] = (_Float16)a.x; o[1] = (_Float16)a.y; o[2] = (_Float16)a.z; o[3] = (_Float16)a.w;
    o[4] = (_Float16)b.x; o[5] = (_Float16)b.y; o[6] = (_Float16)b.z; o[7] = (_Float16)b.w;
    ((f16x8*)out)[i] = o;
}

// ---------- VT[b][e][q] = Q[b][q][e] via LDS tile transpose (R11-proven) ----------
__global__ __launch_bounds__(256) void make_vt_kernel(const float* __restrict__ Q,
                                                      _Float16* __restrict__ VT) {
    __shared__ float t[64][65];
    const int tid = threadIdx.x;
    const int q0 = blockIdx.x * 64, e0 = blockIdx.y * 64, b = blockIdx.z;
    const int rr = tid >> 4, cc = (tid & 15) * 4;
#pragma unroll
    for (int i = 0; i < 4; ++i) {
        const int row = i * 16 + rr;
        const float4 v = *(const float4*)(Q + ((size_t)b * LQ + q0 + row) * EMB + e0 + cc);
        t[row][cc + 0] = v.x; t[row][cc + 1] = v.y; t[row][cc + 2] = v.z; t[row][cc + 3] = v.w;
    }
    __syncthreads();
#pragma unroll
    for (int i = 0; i < 4; ++i) {
        const int erow = i * 16 + rr;
        f16x4 v;
#pragma unroll
        for (int j = 0; j < 4; ++j) v[j] = (_Float16)t[cc + j][erow];
        *(f16x4*)(VT + ((size_t)b * EMB + e0 + erow) * LQ + q0 + cc) = v;
    }
}

// Stage a 128-row x 64-hw f16 tile (256 threads, r2-proven).
__device__ __forceinline__ void stage_tile(const _Float16* g, _Float16* l, int tid) {
#pragma unroll
    for (int i = 0; i < 4; ++i) {
        const int idx = i * 256 + tid;
        const int row = idx >> 3, ch = idx & 7;
        gload16(g + (size_t)row * EMB + ((ch ^ (row & 7)) * 8), l + (size_t)idx * 8);
    }
}

// Stage a 64-row x 64-hw f16 tile (256 threads).
__device__ __forceinline__ void stage_d64(const _Float16* g, _Float16* l, int tid) {
#pragma unroll
    for (int i = 0; i < 2; ++i) {
        const int idx = i * 256 + tid;
        const int row = idx >> 3, ch = idx & 7;
        gload16(g + (size_t)row * EMB + ((ch ^ (row & 7)) * 8), l + (size_t)idx * 8);
    }
}

// ---------- 256x256 8-phase projection GEMM, A read DIRECTLY as f32 ----------
// Structure = R9's proven 8-phase (phases, barriers, B-path, reads identical).
// Only A-staging changed: gload_lds -> {issue f32 loads at P1/P5, cvt + swizzled
// ds_write at P4/P8} (T14). ds_write target region & timing identical to R9's
// A STAGE_PAIR slots, so region-freedom is inherited.
// LEDGER (B retirement now via compiler auto-waits on the f32 A-loads):
//   order/iter: fA(P1)[8] < B(kt2)(P3)[4] < fA2(P5)[8] < B(kt3)(P7)[4].
//   P4 WRITE_A(fA): auto vmcnt wait for fA retires everything <= P1 (incl. prev
//     iter's B(kt3)(P7,j-1)) -> slot1B ready before P5 reads. ✓
//   P8 WRITE_A(fA2): auto-wait for fA2 (P5) retires B(kt2)(P3) -> slot0B ready
//     before P1(j+1) reads. ✓   Prologue: auto-wait for fA(kt1) retires B(0). ✓
//   Tail j=5: no issues -> manual VMW(0) at P4 drains B(11) before P5 reads. ✓
//   Visibility: lgkmcnt(0) after each WRITE_A, before its trailing BAR. ✓
__global__ __launch_bounds__(512, 2) void proj8f_kernel(
    const float* __restrict__ doc, const float* __restrict__ query,
    const _Float16* __restrict__ W16, const float* __restrict__ bias,
    _Float16* __restrict__ OUT) {
    extern __shared__ _Float16 smem[];  // 65536 hw = 128 KB
    const int tid = threadIdx.x, wave = tid >> 6, lane = tid & 63;
    const int lr = lane & 15, lkg = lane >> 4;
    const int wr = wave >> 2, wc = wave & 3;

    const int nwg = gridDim.x, cpx = nwg >> 3;
    const int swz = (blockIdx.x & 7) * cpx + (blockIdx.x >> 3);
    const int rowblk = swz / 3, colblk = swz - rowblk * 3;
    const int row0 = rowblk * 256, col0 = colblk * 256;

    // A source: doc rows 0..32767 f32, query rows 32768..36863 f32
    const float* gAf = (rowblk < 128) ? doc + (size_t)row0 * EMB
                                      : query + (size_t)(row0 - 32768) * EMB;
    const _Float16* gB0 = W16 + (size_t)col0 * EMB;
    const _Float16* gB1 = W16 + (size_t)(col0 + 128) * EMB;

    // B staging coords (gload_lds, linear LDS dest, inverse-swizzled source)
    const int r0_ = tid >> 3, c0_ = (((tid & 7) ^ (r0_ & 7)) * 8);
    const int r1_ = (512 + tid) >> 3, c1_ = ((((512 + tid) & 7) ^ (r1_ & 7)) * 8);
    const int lo0 = tid * 8, lo1 = (512 + tid) * 8;

    // A staging coords: 4 chunks/thread over 256 rows x 8 chunks (linear global,
    // swizzled ds_write dest -> reader's SWZ identity holds)
    int arow_[4], ach_[4];
#pragma unroll
    for (int w = 0; w < 4; ++w) {
        const int c = w * 512 + tid;
        arow_[w] = c >> 3; ach_[w] = c & 7;
    }
    float4 fA[4][2];

#define ISSUE_A(kt) do { _Pragma("unroll") for (int w_ = 0; w_ < 4; ++w_) { \
        const float* s_ = gAf + (size_t)arow_[w_] * EMB + (kt) * 64 + ach_[w_] * 8; \
        fA[w_][0] = *(const float4*)s_; fA[w_][1] = *(const float4*)(s_ + 4); } } while (0)

#define WRITE_A(slot) do { _Pragma("unroll") for (int w_ = 0; w_ < 4; ++w_) { \
        f16x8 v_; \
        v_[0] = (_Float16)fA[w_][0].x; v_[1] = (_Float16)fA[w_][0].y; \
        v_[2] = (_Float16)fA[w_][0].z; v_[3] = (_Float16)fA[w_][0].w; \
        v_[4] = (_Float16)fA[w_][1].x; v_[5] = (_Float16)fA[w_][1].y; \
        v_[6] = (_Float16)fA[w_][1].z; v_[7] = (_Float16)fA[w_][1].w; \
        *(f16x8*)(smem + (slot) * 32768 + (arow_[w_] >> 7) * 8192 \
                  + SWZ(arow_[w_] & 127, ach_[w_])) = v_; } } while (0)

#define STAGE_B(kt, lbase) do { \
    const _Float16* s0_ = gB0 + (kt) * 64; const _Float16* s1_ = gB1 + (kt) * 64; \
    _Float16* d_ = (lbase); \
    gload16(s0_ + (size_t)r0_ * EMB + c0_, d_ + lo0); \
    gload16(s0_ + (size_t)r1_ * EMB + c1_, d_ + lo1); \
    gload16(s1_ + (size_t)r0_ * EMB + c0_, d_ + 8192 + lo0); \
    gload16(s1_ + (size_t)r1_ * EMB + c1_, d_ + 8192 + lo1); } while (0)

    f32x4 acc[8][4];
#pragma unroll
    for (int m = 0; m < 8; ++m)
#pragma unroll
        for (int n = 0; n < 4; ++n) acc[m][n] = (f32x4){0.f, 0.f, 0.f, 0.f};

    f16x8 aF[4][2], bF[4][2];
    const int bro = (wc & 1) * 64;

#define READ_A(slot, MH) do { _Float16* ab_ = smem + (slot) * 32768 + wr * 8192; \
    _Pragma("unroll") for (int mm = 0; mm < 4; ++mm) _Pragma("unroll") for (int ks = 0; ks < 2; ++ks) \
        aF[mm][ks] = *(const f16x8*)(ab_ + SWZ(((MH) * 4 + mm) * 16 + lr, ks * 4 + lkg)); } while (0)
#define READ_B(slot, NH) do { _Float16* bb_ = smem + (slot) * 32768 + 16384 + (wc >> 1) * 8192; \
    _Pragma("unroll") for (int nn = 0; nn < 2; ++nn) _Pragma("unroll") for (int ks = 0; ks < 2; ++ks) \
        bF[(NH) * 2 + nn][ks] = *(const f16x8*)(bb_ + SWZ(bro + ((NH) * 2 + nn) * 16 + lr, ks * 4 + lkg)); } while (0)
#define MFMA_Q(MH, NH) do { __builtin_amdgcn_s_setprio(1); \
    _Pragma("unroll") for (int mm = 0; mm < 4; ++mm) _Pragma("unroll") for (int nn = 0; nn < 2; ++nn) \
    _Pragma("unroll") for (int ks = 0; ks < 2; ++ks) \
        acc[(MH) * 4 + mm][(NH) * 2 + nn] = __builtin_amdgcn_mfma_f32_16x16x32_f16( \
            aF[mm][ks], bF[(NH) * 2 + nn][ks], acc[(MH) * 4 + mm][(NH) * 2 + nn], 0, 0, 0); \
    __builtin_amdgcn_s_setprio(0); } while (0)

    // prologue: kt0 -> slot0, kt1 -> slot1
    ISSUE_A(0);
    STAGE_B(0, smem + 16384);
    WRITE_A(0);                 // auto-wait retires fA(kt0)
    ISSUE_A(1);
    STAGE_B(1, smem + 32768 + 16384);
    WRITE_A(1);                 // auto-wait retires fA(kt1) + B(0); leaves B(1)
    LGKM_FLUSH();
    BAR();

#pragma unroll 1
    for (int j = 0; j < 6; ++j) {
        const int kt2 = 2 * j + 2, kt3 = 2 * j + 3;
        // P1: issue next slot0-A f32; read slot0 B + A(MH0)
        if (j < 5) ISSUE_A(kt2);
        READ_B(0, 0); READ_B(0, 1); READ_A(0, 0);
        BAR(); LGKM0(); MFMA_Q(0, 0); BAR();
        // P2: pure MFMA
        BAR(); LGKM0(); MFMA_Q(0, 1); BAR();
        // P3: read slot0 A(MH1); stage next slot0-B
        READ_A(0, 1);
        if (j < 5) STAGE_B(kt2, smem + 16384);
        BAR(); LGKM0(); MFMA_Q(1, 0); BAR();
        // P4: cvt+write slot0-A (auto vmcnt wait); tail drains
        if (j < 5) { WRITE_A(0); LGKM_FLUSH(); }
        else       { VMW(0); }
        BAR(); LGKM0(); MFMA_Q(1, 1); BAR();
        // P5: issue next slot1-A f32; read slot1 B + A(MH0)
        if (j < 5) ISSUE_A(kt3);
        READ_B(1, 0); READ_B(1, 1); READ_A(1, 0);
        BAR(); LGKM0(); MFMA_Q(0, 0); BAR();
        // P6: pure MFMA
        BAR(); LGKM0(); MFMA_Q(0, 1); BAR();
        // P7: read slot1 A(MH1); stage next slot1-B
        READ_A(1, 1);
        if (j < 5) STAGE_B(kt3, smem + 32768 + 16384);
        BAR(); LGKM0(); MFMA_Q(1, 0); BAR();
        // P8: cvt+write slot1-A (auto-wait retires B(kt2) too)
        if (j < 5) { WRITE_A(1); LGKM_FLUSH(); }
        BAR(); LGKM0(); MFMA_Q(1, 1); BAR();
    }

    // epilogue: bias + ReLU + f16 store
    const int crow = lkg * 4;
#pragma unroll
    for (int n = 0; n < 4; ++n) {
        const int gc = col0 + wc * 64 + n * 16 + lr;
        const float bv = bias[gc];
#pragma unroll
        for (int m = 0; m < 8; ++m) {
            const size_t gr = (size_t)row0 + wr * 128 + m * 16 + crow;
#pragma unroll
            for (int r = 0; r < 4; ++r) {
                float v = acc[m][n][r] + bv;
                OUT[(gr + r) * EMB + gc] = (_Float16)(v > 0.f ? v : 0.f);
            }
        }
    }
#undef ISSUE_A
#undef WRITE_A
#undef STAGE_B
#undef READ_A
#undef READ_B
#undef MFMA_Q
}

// ---------- attention: 64 doc rows/block (R11-proven, verbatim) ----------
__global__ __launch_bounds__(256) void attn64_kernel(
    const _Float16* __restrict__ Do, const _Float16* __restrict__ Qo,
    const _Float16* __restrict__ VT, float* __restrict__ OUT) {
    __shared__ __align__(16) _Float16 smem[24576];
    const int tid = threadIdx.x, wave = tid >> 6, lane = tid & 63;
    const int lr = lane & 15, lkg = lane >> 4;

    const int l = blockIdx.x;
    const int x = l & 7, i = l >> 3;
    const int b = x * 4 + (i >> 4), dblk = i & 15;

    const _Float16* gd = Do + ((size_t)b * LD + dblk * 64) * EMB;
    const _Float16* gq = Qo + (size_t)b * LQ * EMB;

    f32x4 s[8];
#pragma unroll
    for (int n = 0; n < 8; ++n) s[n] = (f32x4){0.f, 0.f, 0.f, 0.f};

    stage_d64(gd, smem, tid);
    stage_tile(gq, smem + 4096, tid);
    int cur = 0;
    for (int it = 0; it < 12; ++it) {
        __syncthreads();
        if (it < 11) {
            stage_d64(gd + (it + 1) * 64, smem + (cur ^ 1) * 12288, tid);
            stage_tile(gq + (it + 1) * 64, smem + (cur ^ 1) * 12288 + 4096, tid);
        }
        const _Float16* sD = smem + cur * 12288;
        const _Float16* sQ = sD + 4096;
#pragma unroll
        for (int kk = 0; kk < 2; ++kk) {
            const int ch = kk * 4 + lkg;
            const f16x8 am = *(const f16x8*)(sD + SWZ(wave * 16 + lr, ch));
#pragma unroll
            for (int n = 0; n < 8; ++n) {
                const f16x8 bq = *(const f16x8*)(sQ + SWZ(n * 16 + lr, ch));
                s[n] = __builtin_amdgcn_mfma_f32_16x16x32_f16(am, bq, s[n], 0, 0, 0);
            }
        }
        cur ^= 1;
    }
    __syncthreads();

    _Float16 (*P)[136] = (_Float16 (*)[136])smem;
    const int crow = lkg * 4;
#pragma unroll
    for (int r = 0; r < 4; ++r) {
        float mx = -1e30f;
#pragma unroll
        for (int n = 0; n < 8; ++n) mx = fmaxf(mx, s[n][r]);
#pragma unroll
        for (int off = 1; off < 16; off <<= 1) mx = fmaxf(mx, __shfl_xor(mx, off));
        float p[8], sum = 0.f;
#pragma unroll
        for (int n = 0; n < 8; ++n) { p[n] = __expf(s[n][r] - mx); sum += p[n]; }
#pragma unroll
        for (int off = 1; off < 16; off <<= 1) sum += __shfl_xor(sum, off);
        const float inv = 1.f / sum;
        const int row = wave * 16 + crow + r;
#pragma unroll
        for (int n = 0; n < 8; ++n) P[row][n * 16 + lr] = (_Float16)(p[n] * inv);
    }
    __syncthreads();

    const _Float16* vtb = VT + (size_t)b * EMB * LQ;
    const size_t dbase = (size_t)b * LD + dblk * 64 + wave * 16 + crow;
#pragma unroll 1
    for (int nc = 0; nc < 6; ++nc) {
        f32x4 o[8];
#pragma unroll
        for (int t = 0; t < 8; ++t) o[t] = (f32x4){0.f, 0.f, 0.f, 0.f};
#pragma unroll
        for (int ks = 0; ks < 4; ++ks) {
            const f16x8 am = *(const f16x8*)(&P[wave * 16 + lr][ks * 32 + lkg * 8]);
#pragma unroll
            for (int t = 0; t < 8; ++t) {
                const f16x8 bv = *(const f16x8*)(vtb + (size_t)(nc * 128 + t * 16 + lr) * LQ
                                                 + ks * 32 + lkg * 8);
                o[t] = __builtin_amdgcn_mfma_f32_16x16x32_f16(am, bv, o[t], 0, 0, 0);
            }
        }
#pragma unroll
        for (int t = 0; t < 8; ++t) {
            const int e = nc * 128 + t * 16 + lr;
#pragma unroll
            for (int r = 0; r < 4; ++r)
                OUT[(dbase + r) * EMB + e] = o[t][r];
        }
    }
}

extern "C" void kernel_launch(void* const* d_in, const int* in_sizes, int n_in,
                              void* d_out, int out_size, void* d_ws, size_t ws_size,
                              hipStream_t stream) {
    const float* doc   = (const float*)d_in[0];   // [32,1024,768]
    const float* query = (const float*)d_in[1];   // [32,128,768]
    const float* W     = (const float*)d_in[2];   // [768,768]
    const float* bias  = (const float*)d_in[3];   // [768]
    float* out = (float*)d_out;                   // [32,1024,768] f32

    const size_t nW  = (size_t)EMB * EMB;        // 589824
    const size_t nVT = (size_t)NB * EMB * LQ;    // 3145728
    const size_t nDo = (size_t)NB * LD * EMB;    // 25165824
    const size_t nQo = (size_t)NB * LQ * EMB;    // 3145728
    const size_t need = (nW + nVT + nDo + nQo) * sizeof(_Float16);  // ~64.1 MB
    if (ws_size < need) return;

    _Float16* W16 = (_Float16*)d_ws;
    _Float16* VT  = W16 + nW;
    _Float16* Do  = VT + nVT;    // Do || Qo contiguous: merged proj output
    _Float16* Qo  = Do + nDo;

    cvt8_kernel<<<(int)(nW / 8 / 256), 256, 0, stream>>>(W, W16, (int)(nW / 8));
    make_vt_kernel<<<dim3(2, 12, NB), 256, 0, stream>>>(query, VT);

    // merged projection reading f32 activations directly (no activation cvt pass):
    // M = 36864 -> 144 rowblks x 3 colblks = 432 blocks, 128KB LDS
    hipFuncSetAttribute(reinterpret_cast<const void*>(&proj8f_kernel),
                        hipFuncAttributeMaxDynamicSharedMemorySize, 131072);
    proj8f_kernel<<<dim3(144 * 3), 512, 131072, stream>>>(doc, query, W16, bias, Do);

    attn64_kernel<<<dim3(NB * 16), 256, 0, stream>>>(Do, Qo, VT, out);
}

// Round 14
// 163.220 us; speedup vs baseline: 1.0080x; 1.0080x over previous
//
#include <hip/hip_runtime.h>

typedef _Float16 f16x8 __attribute__((ext_vector_type(8)));
typedef _Float16 f16x4 __attribute__((ext_vector_type(4)));
typedef float f32x4 __attribute__((ext_vector_type(4)));

#define EMB 768
#define LQ 128
#define LD 1024
#define NB 32

typedef const __attribute__((address_space(1))) char gas_char;
typedef __attribute__((address_space(3))) char las_char;

__device__ __forceinline__ void gload16(const void* g, void* l) {
    __builtin_amdgcn_global_load_lds((gas_char*)g, (las_char*)l, 16, 0, 0);
}

// 128B-row tiles: 8 chunks of 16B, XOR row&7. 0 bank conflicts measured (R7-R11).
#define SWZ(row, ch) ((row) * 64 + ((((ch) ^ ((row) & 7))) * 8))

#define BAR() asm volatile("s_barrier" ::: "memory")
#define LGKM0() do { asm volatile("s_waitcnt lgkmcnt(0)" ::: "memory"); \
                     __builtin_amdgcn_sched_barrier(0); } while (0)
#define VMW(N) asm volatile("s_waitcnt vmcnt(" #N ")" ::: "memory")
#define LGKM_FLUSH() asm volatile("s_waitcnt lgkmcnt(0)" ::: "memory")

// ---------- f32 -> f16, 8 elems/thread (W only) ----------
__global__ void cvt8_kernel(const float* __restrict__ in, _Float16* __restrict__ out, int n8) {
    int i = blockIdx.x * 256 + threadIdx.x;
    if (i >= n8) return;
    const float4 a = ((const float4*)in)[2 * i];
    const float4 b = ((const float4*)in)[2 * i + 1];
    f16x8 o;
    o[0] = (_Float16)a.x; o[1] = (_Float16)a.y; o[2] = (_Float16)a.z; o[3] = (_Float16)a.w;
    o[4] = (_Float16)b.x; o[5] = (_Float16)b.y; o[6] = (_Float16)b.z; o[7] = (_Float16)b.w;
    ((f16x8*)out)[i] = o;
}

// ---------- VT[b][e][q] = Q[b][q][e] via LDS tile transpose (R11-proven) ----------
__global__ __launch_bounds__(256) void make_vt_kernel(const float* __restrict__ Q,
                                                      _Float16* __restrict__ VT) {
    __shared__ float t[64][65];
    const int tid = threadIdx.x;
    const int q0 = blockIdx.x * 64, e0 = blockIdx.y * 64, b = blockIdx.z;
    const int rr = tid >> 4, cc = (tid & 15) * 4;
#pragma unroll
    for (int i = 0; i < 4; ++i) {
        const int row = i * 16 + rr;
        const float4 v = *(const float4*)(Q + ((size_t)b * LQ + q0 + row) * EMB + e0 + cc);
        t[row][cc + 0] = v.x; t[row][cc + 1] = v.y; t[row][cc + 2] = v.z; t[row][cc + 3] = v.w;
    }
    __syncthreads();
#pragma unroll
    for (int i = 0; i < 4; ++i) {
        const int erow = i * 16 + rr;
        f16x4 v;
#pragma unroll
        for (int j = 0; j < 4; ++j) v[j] = (_Float16)t[cc + j][erow];
        *(f16x4*)(VT + ((size_t)b * EMB + e0 + erow) * LQ + q0 + cc) = v;
    }
}

// Stage a 128-row x 64-hw f16 tile (256 threads, r2-proven).
__device__ __forceinline__ void stage_tile(const _Float16* g, _Float16* l, int tid) {
#pragma unroll
    for (int i = 0; i < 4; ++i) {
        const int idx = i * 256 + tid;
        const int row = idx >> 3, ch = idx & 7;
        gload16(g + (size_t)row * EMB + ((ch ^ (row & 7)) * 8), l + (size_t)idx * 8);
    }
}

// Stage a 64-row x 64-hw f16 tile (256 threads).
__device__ __forceinline__ void stage_d64(const _Float16* g, _Float16* l, int tid) {
#pragma unroll
    for (int i = 0; i < 2; ++i) {
        const int idx = i * 256 + tid;
        const int row = idx >> 3, ch = idx & 7;
        gload16(g + (size_t)row * EMB + ((ch ^ (row & 7)) * 8), l + (size_t)idx * 8);
    }
}

// ---------- 256x256 8-phase projection GEMM, A read DIRECTLY as f32 ----------
// Structure = R9's proven 8-phase (phases, barriers, B-path, reads identical).
// Only A-staging changed: gload_lds -> {issue f32 loads at P1/P5, cvt + swizzled
// ds_write at P4/P8} (T14). ds_write target region & timing identical to R9's
// A STAGE_PAIR slots, so region-freedom is inherited.
// LEDGER (B retirement now via compiler auto-waits on the f32 A-loads):
//   order/iter: fA(P1)[8] < B(kt2)(P3)[4] < fA2(P5)[8] < B(kt3)(P7)[4].
//   P4 WRITE_A(fA): auto vmcnt wait for fA retires everything <= P1 (incl. prev
//     iter's B(kt3)(P7,j-1)) -> slot1B ready before P5 reads. ✓
//   P8 WRITE_A(fA2): auto-wait for fA2 (P5) retires B(kt2)(P3) -> slot0B ready
//     before P1(j+1) reads. ✓   Prologue: auto-wait for fA(kt1) retires B(0). ✓
//   Tail j=5: no issues -> manual VMW(0) at P4 drains B(11) before P5 reads. ✓
//   Visibility: lgkmcnt(0) after each WRITE_A, before its trailing BAR. ✓
__global__ __launch_bounds__(512, 2) void proj8f_kernel(
    const float* __restrict__ doc, const float* __restrict__ query,
    const _Float16* __restrict__ W16, const float* __restrict__ bias,
    _Float16* __restrict__ OUT) {
    extern __shared__ _Float16 smem[];  // 65536 hw = 128 KB
    const int tid = threadIdx.x, wave = tid >> 6, lane = tid & 63;
    const int lr = lane & 15, lkg = lane >> 4;
    const int wr = wave >> 2, wc = wave & 3;

    const int nwg = gridDim.x, cpx = nwg >> 3;
    const int swz = (blockIdx.x & 7) * cpx + (blockIdx.x >> 3);
    const int rowblk = swz / 3, colblk = swz - rowblk * 3;
    const int row0 = rowblk * 256, col0 = colblk * 256;

    // A source: doc rows 0..32767 f32, query rows 32768..36863 f32
    const float* gAf = (rowblk < 128) ? doc + (size_t)row0 * EMB
                                      : query + (size_t)(row0 - 32768) * EMB;
    const _Float16* gB0 = W16 + (size_t)col0 * EMB;
    const _Float16* gB1 = W16 + (size_t)(col0 + 128) * EMB;

    // B staging coords (gload_lds, linear LDS dest, inverse-swizzled source)
    const int r0_ = tid >> 3, c0_ = (((tid & 7) ^ (r0_ & 7)) * 8);
    const int r1_ = (512 + tid) >> 3, c1_ = ((((512 + tid) & 7) ^ (r1_ & 7)) * 8);
    const int lo0 = tid * 8, lo1 = (512 + tid) * 8;

    // A staging coords: 4 chunks/thread over 256 rows x 8 chunks (linear global,
    // swizzled ds_write dest -> reader's SWZ identity holds)
    int arow_[4], ach_[4];
#pragma unroll
    for (int w = 0; w < 4; ++w) {
        const int c = w * 512 + tid;
        arow_[w] = c >> 3; ach_[w] = c & 7;
    }
    float4 fA[4][2];

#define ISSUE_A(kt) do { _Pragma("unroll") for (int w_ = 0; w_ < 4; ++w_) { \
        const float* s_ = gAf + (size_t)arow_[w_] * EMB + (kt) * 64 + ach_[w_] * 8; \
        fA[w_][0] = *(const float4*)s_; fA[w_][1] = *(const float4*)(s_ + 4); } } while (0)

#define WRITE_A(slot) do { _Pragma("unroll") for (int w_ = 0; w_ < 4; ++w_) { \
        f16x8 v_; \
        v_[0] = (_Float16)fA[w_][0].x; v_[1] = (_Float16)fA[w_][0].y; \
        v_[2] = (_Float16)fA[w_][0].z; v_[3] = (_Float16)fA[w_][0].w; \
        v_[4] = (_Float16)fA[w_][1].x; v_[5] = (_Float16)fA[w_][1].y; \
        v_[6] = (_Float16)fA[w_][1].z; v_[7] = (_Float16)fA[w_][1].w; \
        *(f16x8*)(smem + (slot) * 32768 + (arow_[w_] >> 7) * 8192 \
                  + SWZ(arow_[w_] & 127, ach_[w_])) = v_; } } while (0)

#define STAGE_B(kt, lbase) do { \
    const _Float16* s0_ = gB0 + (kt) * 64; const _Float16* s1_ = gB1 + (kt) * 64; \
    _Float16* d_ = (lbase); \
    gload16(s0_ + (size_t)r0_ * EMB + c0_, d_ + lo0); \
    gload16(s0_ + (size_t)r1_ * EMB + c1_, d_ + lo1); \
    gload16(s1_ + (size_t)r0_ * EMB + c0_, d_ + 8192 + lo0); \
    gload16(s1_ + (size_t)r1_ * EMB + c1_, d_ + 8192 + lo1); } while (0)

    f32x4 acc[8][4];
#pragma unroll
    for (int m = 0; m < 8; ++m)
#pragma unroll
        for (int n = 0; n < 4; ++n) acc[m][n] = (f32x4){0.f, 0.f, 0.f, 0.f};

    f16x8 aF[4][2], bF[4][2];
    const int bro = (wc & 1) * 64;

#define READ_A(slot, MH) do { _Float16* ab_ = smem + (slot) * 32768 + wr * 8192; \
    _Pragma("unroll") for (int mm = 0; mm < 4; ++mm) _Pragma("unroll") for (int ks = 0; ks < 2; ++ks) \
        aF[mm][ks] = *(const f16x8*)(ab_ + SWZ(((MH) * 4 + mm) * 16 + lr, ks * 4 + lkg)); } while (0)
#define READ_B(slot, NH) do { _Float16* bb_ = smem + (slot) * 32768 + 16384 + (wc >> 1) * 8192; \
    _Pragma("unroll") for (int nn = 0; nn < 2; ++nn) _Pragma("unroll") for (int ks = 0; ks < 2; ++ks) \
        bF[(NH) * 2 + nn][ks] = *(const f16x8*)(bb_ + SWZ(bro + ((NH) * 2 + nn) * 16 + lr, ks * 4 + lkg)); } while (0)
#define MFMA_Q(MH, NH) do { __builtin_amdgcn_s_setprio(1); \
    _Pragma("unroll") for (int mm = 0; mm < 4; ++mm) _Pragma("unroll") for (int nn = 0; nn < 2; ++nn) \
    _Pragma("unroll") for (int ks = 0; ks < 2; ++ks) \
        acc[(MH) * 4 + mm][(NH) * 2 + nn] = __builtin_amdgcn_mfma_f32_16x16x32_f16( \
            aF[mm][ks], bF[(NH) * 2 + nn][ks], acc[(MH) * 4 + mm][(NH) * 2 + nn], 0, 0, 0); \
    __builtin_amdgcn_s_setprio(0); } while (0)

    // prologue: kt0 -> slot0, kt1 -> slot1
    ISSUE_A(0);
    STAGE_B(0, smem + 16384);
    WRITE_A(0);                 // auto-wait retires fA(kt0)
    ISSUE_A(1);
    STAGE_B(1, smem + 32768 + 16384);
    WRITE_A(1);                 // auto-wait retires fA(kt1) + B(0); leaves B(1)
    LGKM_FLUSH();
    BAR();

#pragma unroll 1
    for (int j = 0; j < 6; ++j) {
        const int kt2 = 2 * j + 2, kt3 = 2 * j + 3;
        // P1: issue next slot0-A f32; read slot0 B + A(MH0)
        if (j < 5) ISSUE_A(kt2);
        READ_B(0, 0); READ_B(0, 1); READ_A(0, 0);
        BAR(); LGKM0(); MFMA_Q(0, 0); BAR();
        // P2: pure MFMA
        BAR(); LGKM0(); MFMA_Q(0, 1); BAR();
        // P3: read slot0 A(MH1); stage next slot0-B
        READ_A(0, 1);
        if (j < 5) STAGE_B(kt2, smem + 16384);
        BAR(); LGKM0(); MFMA_Q(1, 0); BAR();
        // P4: cvt+write slot0-A (auto vmcnt wait); tail drains
        if (j < 5) { WRITE_A(0); LGKM_FLUSH(); }
        else       { VMW(0); }
        BAR(); LGKM0(); MFMA_Q(1, 1); BAR();
        // P5: issue next slot1-A f32; read slot1 B + A(MH0)
        if (j < 5) ISSUE_A(kt3);
        READ_B(1, 0); READ_B(1, 1); READ_A(1, 0);
        BAR(); LGKM0(); MFMA_Q(0, 0); BAR();
        // P6: pure MFMA
        BAR(); LGKM0(); MFMA_Q(0, 1); BAR();
        // P7: read slot1 A(MH1); stage next slot1-B
        READ_A(1, 1);
        if (j < 5) STAGE_B(kt3, smem + 32768 + 16384);
        BAR(); LGKM0(); MFMA_Q(1, 0); BAR();
        // P8: cvt+write slot1-A (auto-wait retires B(kt2) too)
        if (j < 5) { WRITE_A(1); LGKM_FLUSH(); }
        BAR(); LGKM0(); MFMA_Q(1, 1); BAR();
    }

    // epilogue: bias + ReLU + f16 store
    const int crow = lkg * 4;
#pragma unroll
    for (int n = 0; n < 4; ++n) {
        const int gc = col0 + wc * 64 + n * 16 + lr;
        const float bv = bias[gc];
#pragma unroll
        for (int m = 0; m < 8; ++m) {
            const size_t gr = (size_t)row0 + wr * 128 + m * 16 + crow;
#pragma unroll
            for (int r = 0; r < 4; ++r) {
                float v = acc[m][n][r] + bv;
                OUT[(gr + r) * EMB + gc] = (_Float16)(v > 0.f ? v : 0.f);
            }
        }
    }
#undef ISSUE_A
#undef WRITE_A
#undef STAGE_B
#undef READ_A
#undef READ_B
#undef MFMA_Q
}

// ---------- attention: 64 doc rows/block (R11-proven, verbatim) ----------
__global__ __launch_bounds__(256) void attn64_kernel(
    const _Float16* __restrict__ Do, const _Float16* __restrict__ Qo,
    const _Float16* __restrict__ VT, float* __restrict__ OUT) {
    __shared__ __align__(16) _Float16 smem[24576];
    const int tid = threadIdx.x, wave = tid >> 6, lane = tid & 63;
    const int lr = lane & 15, lkg = lane >> 4;

    const int l = blockIdx.x;
    const int x = l & 7, i = l >> 3;
    const int b = x * 4 + (i >> 4), dblk = i & 15;

    const _Float16* gd = Do + ((size_t)b * LD + dblk * 64) * EMB;
    const _Float16* gq = Qo + (size_t)b * LQ * EMB;

    f32x4 s[8];
#pragma unroll
    for (int n = 0; n < 8; ++n) s[n] = (f32x4){0.f, 0.f, 0.f, 0.f};

    stage_d64(gd, smem, tid);
    stage_tile(gq, smem + 4096, tid);
    int cur = 0;
    for (int it = 0; it < 12; ++it) {
        __syncthreads();
        if (it < 11) {
            stage_d64(gd + (it + 1) * 64, smem + (cur ^ 1) * 12288, tid);
            stage_tile(gq + (it + 1) * 64, smem + (cur ^ 1) * 12288 + 4096, tid);
        }
        const _Float16* sD = smem + cur * 12288;
        const _Float16* sQ = sD + 4096;
#pragma unroll
        for (int kk = 0; kk < 2; ++kk) {
            const int ch = kk * 4 + lkg;
            const f16x8 am = *(const f16x8*)(sD + SWZ(wave * 16 + lr, ch));
#pragma unroll
            for (int n = 0; n < 8; ++n) {
                const f16x8 bq = *(const f16x8*)(sQ + SWZ(n * 16 + lr, ch));
                s[n] = __builtin_amdgcn_mfma_f32_16x16x32_f16(am, bq, s[n], 0, 0, 0);
            }
        }
        cur ^= 1;
    }
    __syncthreads();

    _Float16 (*P)[136] = (_Float16 (*)[136])smem;
    const int crow = lkg * 4;
#pragma unroll
    for (int r = 0; r < 4; ++r) {
        float mx = -1e30f;
#pragma unroll
        for (int n = 0; n < 8; ++n) mx = fmaxf(mx, s[n][r]);
#pragma unroll
        for (int off = 1; off < 16; off <<= 1) mx = fmaxf(mx, __shfl_xor(mx, off));
        float p[8], sum = 0.f;
#pragma unroll
        for (int n = 0; n < 8; ++n) { p[n] = __expf(s[n][r] - mx); sum += p[n]; }
#pragma unroll
        for (int off = 1; off < 16; off <<= 1) sum += __shfl_xor(sum, off);
        const float inv = 1.f / sum;
        const int row = wave * 16 + crow + r;
#pragma unroll
        for (int n = 0; n < 8; ++n) P[row][n * 16 + lr] = (_Float16)(p[n] * inv);
    }
    __syncthreads();

    const _Float16* vtb = VT + (size_t)b * EMB * LQ;
    const size_t dbase = (size_t)b * LD + dblk * 64 + wave * 16 + crow;
#pragma unroll 1
    for (int nc = 0; nc < 6; ++nc) {
        f32x4 o[8];
#pragma unroll
        for (int t = 0; t < 8; ++t) o[t] = (f32x4){0.f, 0.f, 0.f, 0.f};
#pragma unroll
        for (int ks = 0; ks < 4; ++ks) {
            const f16x8 am = *(const f16x8*)(&P[wave * 16 + lr][ks * 32 + lkg * 8]);
#pragma unroll
            for (int t = 0; t < 8; ++t) {
                const f16x8 bv = *(const f16x8*)(vtb + (size_t)(nc * 128 + t * 16 + lr) * LQ
                                                 + ks * 32 + lkg * 8);
                o[t] = __builtin_amdgcn_mfma_f32_16x16x32_f16(am, bv, o[t], 0, 0, 0);
            }
        }
#pragma unroll
        for (int t = 0; t < 8; ++t) {
            const int e = nc * 128 + t * 16 + lr;
#pragma unroll
            for (int r = 0; r < 4; ++r)
                OUT[(dbase + r) * EMB + e] = o[t][r];
        }
    }
}

extern "C" void kernel_launch(void* const* d_in, const int* in_sizes, int n_in,
                              void* d_out, int out_size, void* d_ws, size_t ws_size,
                              hipStream_t stream) {
    const float* doc   = (const float*)d_in[0];   // [32,1024,768]
    const float* query = (const float*)d_in[1];   // [32,128,768]
    const float* W     = (const float*)d_in[2];   // [768,768]
    const float* bias  = (const float*)d_in[3];   // [768]
    float* out = (float*)d_out;                   // [32,1024,768] f32

    const size_t nW  = (size_t)EMB * EMB;        // 589824
    const size_t nVT = (size_t)NB * EMB * LQ;    // 3145728
    const size_t nDo = (size_t)NB * LD * EMB;    // 25165824
    const size_t nQo = (size_t)NB * LQ * EMB;    // 3145728
    const size_t need = (nW + nVT + nDo + nQo) * sizeof(_Float16);  // ~64.1 MB
    if (ws_size < need) return;

    _Float16* W16 = (_Float16*)d_ws;
    _Float16* VT  = W16 + nW;
    _Float16* Do  = VT + nVT;    // Do || Qo contiguous: merged proj output
    _Float16* Qo  = Do + nDo;

    cvt8_kernel<<<(int)(nW / 8 / 256), 256, 0, stream>>>(W, W16, (int)(nW / 8));
    make_vt_kernel<<<dim3(2, 12, NB), 256, 0, stream>>>(query, VT);

    // merged projection reading f32 activations directly (no activation cvt pass):
    // M = 36864 -> 144 rowblks x 3 colblks = 432 blocks, 128KB LDS
    hipFuncSetAttribute(reinterpret_cast<const void*>(&proj8f_kernel),
                        hipFuncAttributeMaxDynamicSharedMemorySize, 131072);
    proj8f_kernel<<<dim3(144 * 3), 512, 131072, stream>>>(doc, query, W16, bias, Do);

    attn64_kernel<<<dim3(NB * 16), 256, 0, stream>>>(Do, Qo, VT, out);
}

// Round 15
// 147.195 us; speedup vs baseline: 1.1177x; 1.1089x over previous
//
#include <hip/hip_runtime.h>

typedef _Float16 f16x8 __attribute__((ext_vector_type(8)));
typedef _Float16 f16x4 __attribute__((ext_vector_type(4)));
typedef float f32x4 __attribute__((ext_vector_type(4)));

#define EMB 768
#define LQ 128
#define LD 1024
#define NB 32

typedef const __attribute__((address_space(1))) char gas_char;
typedef __attribute__((address_space(3))) char las_char;

__device__ __forceinline__ void gload16(const void* g, void* l) {
    __builtin_amdgcn_global_load_lds((gas_char*)g, (las_char*)l, 16, 0, 0);
}

// 128B-row tiles: 8 chunks of 16B, XOR row&7. 0 bank conflicts measured (R7-R11).
#define SWZ(row, ch) ((row) * 64 + ((((ch) ^ ((row) & 7))) * 8))

#define BAR() asm volatile("s_barrier" ::: "memory")
#define LGKM0() do { asm volatile("s_waitcnt lgkmcnt(0)" ::: "memory"); \
                     __builtin_amdgcn_sched_barrier(0); } while (0)
#define VMW(N) asm volatile("s_waitcnt vmcnt(" #N ")" ::: "memory")

// ---------- merged f32 -> f16 for doc / query / W (one launch, 3 segments) ----------
#define DOCB 12288   // nDo/8/256
#define QB   1536    // nQo/8/256
#define WB   288     // nW/8/256
__global__ void cvt_all_kernel(const float* __restrict__ doc, const float* __restrict__ query,
                               const float* __restrict__ W, _Float16* __restrict__ doc16,
                               _Float16* __restrict__ q16, _Float16* __restrict__ W16) {
    const int bid = blockIdx.x;
    const float* src;
    _Float16* dst;
    int i;
    if (bid < DOCB)            { src = doc;   dst = doc16; i = bid * 256 + threadIdx.x; }
    else if (bid < DOCB + QB)  { src = query; dst = q16;   i = (bid - DOCB) * 256 + threadIdx.x; }
    else                       { src = W;     dst = W16;   i = (bid - DOCB - QB) * 256 + threadIdx.x; }
    const float4 a = ((const float4*)src)[2 * i];
    const float4 b = ((const float4*)src)[2 * i + 1];
    f16x8 o;
    o[0] = (_Float16)a.x; o[1] = (_Float16)a.y; o[2] = (_Float16)a.z; o[3] = (_Float16)a.w;
    o[4] = (_Float16)b.x; o[5] = (_Float16)b.y; o[6] = (_Float16)b.z; o[7] = (_Float16)b.w;
    ((f16x8*)dst)[i] = o;
}

// ---------- VT[b][e][q] = Q[b][q][e] via LDS tile transpose (R11-proven) ----------
__global__ __launch_bounds__(256) void make_vt_kernel(const float* __restrict__ Q,
                                                      _Float16* __restrict__ VT) {
    __shared__ float t[64][65];
    const int tid = threadIdx.x;
    const int q0 = blockIdx.x * 64, e0 = blockIdx.y * 64, b = blockIdx.z;
    const int rr = tid >> 4, cc = (tid & 15) * 4;
#pragma unroll
    for (int i = 0; i < 4; ++i) {
        const int row = i * 16 + rr;
        const float4 v = *(const float4*)(Q + ((size_t)b * LQ + q0 + row) * EMB + e0 + cc);
        t[row][cc + 0] = v.x; t[row][cc + 1] = v.y; t[row][cc + 2] = v.z; t[row][cc + 3] = v.w;
    }
    __syncthreads();
#pragma unroll
    for (int i = 0; i < 4; ++i) {
        const int erow = i * 16 + rr;
        f16x4 v;
#pragma unroll
        for (int j = 0; j < 4; ++j) v[j] = (_Float16)t[cc + j][erow];
        *(f16x4*)(VT + ((size_t)b * EMB + e0 + erow) * LQ + q0 + cc) = v;
    }
}

// Stage a 128-row x 64-hw f16 tile (256 threads, r2-proven).
__device__ __forceinline__ void stage_tile(const _Float16* g, _Float16* l, int tid) {
#pragma unroll
    for (int i = 0; i < 4; ++i) {
        const int idx = i * 256 + tid;
        const int row = idx >> 3, ch = idx & 7;
        gload16(g + (size_t)row * EMB + ((ch ^ (row & 7)) * 8), l + (size_t)idx * 8);
    }
}

// Stage a 64-row x 64-hw f16 tile (256 threads).
__device__ __forceinline__ void stage_d64(const _Float16* g, _Float16* l, int tid) {
#pragma unroll
    for (int i = 0; i < 2; ++i) {
        const int idx = i * 256 + tid;
        const int row = idx >> 3, ch = idx & 7;
        gload16(g + (size_t)row * EMB + ((ch ^ (row & 7)) * 8), l + (size_t)idx * 8);
    }
}

// ---------- 256x256 8-phase projection GEMM (R9/R11-proven, verbatim) ----------
__global__ __launch_bounds__(512, 2) void proj8_kernel(
    const _Float16* __restrict__ A, const _Float16* __restrict__ W16,
    const float* __restrict__ bias, _Float16* __restrict__ OUT) {
    extern __shared__ _Float16 smem[];  // 65536 hw = 128 KB
    const int tid = threadIdx.x, wave = tid >> 6, lane = tid & 63;
    const int lr = lane & 15, lkg = lane >> 4;
    const int wr = wave >> 2, wc = wave & 3;

    const int nwg = gridDim.x, cpx = nwg >> 3;
    const int swz = (blockIdx.x & 7) * cpx + (blockIdx.x >> 3);
    const int rowblk = swz / 3, colblk = swz - rowblk * 3;
    const int row0 = rowblk * 256, col0 = colblk * 256;

    const int r0_ = tid >> 3, c0_ = (((tid & 7) ^ (r0_ & 7)) * 8);
    const int r1_ = (512 + tid) >> 3, c1_ = ((((512 + tid) & 7) ^ (r1_ & 7)) * 8);
    const int lo0 = tid * 8, lo1 = (512 + tid) * 8;

    const _Float16* gA0 = A + (size_t)row0 * EMB;
    const _Float16* gA1 = A + (size_t)(row0 + 128) * EMB;
    const _Float16* gB0 = W16 + (size_t)col0 * EMB;
    const _Float16* gB1 = W16 + (size_t)(col0 + 128) * EMB;

#define STAGE_PAIR(g0, g1, kt, lbase) do { \
    const _Float16* s0_ = (g0) + (kt) * 64; const _Float16* s1_ = (g1) + (kt) * 64; \
    _Float16* d_ = (lbase); \
    gload16(s0_ + (size_t)r0_ * EMB + c0_, d_ + lo0); \
    gload16(s0_ + (size_t)r1_ * EMB + c1_, d_ + lo1); \
    gload16(s1_ + (size_t)r0_ * EMB + c0_, d_ + 8192 + lo0); \
    gload16(s1_ + (size_t)r1_ * EMB + c1_, d_ + 8192 + lo1); } while (0)

    f32x4 acc[8][4];
#pragma unroll
    for (int m = 0; m < 8; ++m)
#pragma unroll
        for (int n = 0; n < 4; ++n) acc[m][n] = (f32x4){0.f, 0.f, 0.f, 0.f};

    f16x8 aF[4][2], bF[4][2];
    const int bro = (wc & 1) * 64;

#define READ_A(slot, MH) do { _Float16* ab_ = smem + (slot) * 32768 + wr * 8192; \
    _Pragma("unroll") for (int mm = 0; mm < 4; ++mm) _Pragma("unroll") for (int ks = 0; ks < 2; ++ks) \
        aF[mm][ks] = *(const f16x8*)(ab_ + SWZ(((MH) * 4 + mm) * 16 + lr, ks * 4 + lkg)); } while (0)
#define READ_B(slot, NH) do { _Float16* bb_ = smem + (slot) * 32768 + 16384 + (wc >> 1) * 8192; \
    _Pragma("unroll") for (int nn = 0; nn < 2; ++nn) _Pragma("unroll") for (int ks = 0; ks < 2; ++ks) \
        bF[(NH) * 2 + nn][ks] = *(const f16x8*)(bb_ + SWZ(bro + ((NH) * 2 + nn) * 16 + lr, ks * 4 + lkg)); } while (0)
#define MFMA_Q(MH, NH) do { __builtin_amdgcn_s_setprio(1); \
    _Pragma("unroll") for (int mm = 0; mm < 4; ++mm) _Pragma("unroll") for (int nn = 0; nn < 2; ++nn) \
    _Pragma("unroll") for (int ks = 0; ks < 2; ++ks) \
        acc[(MH) * 4 + mm][(NH) * 2 + nn] = __builtin_amdgcn_mfma_f32_16x16x32_f16( \
            aF[mm][ks], bF[(NH) * 2 + nn][ks], acc[(MH) * 4 + mm][(NH) * 2 + nn], 0, 0, 0); \
    __builtin_amdgcn_s_setprio(0); } while (0)

    STAGE_PAIR(gB0, gB1, 0, smem + 16384);
    STAGE_PAIR(gA0, gA1, 0, smem);
    STAGE_PAIR(gB0, gB1, 1, smem + 32768 + 16384);
    STAGE_PAIR(gA0, gA1, 1, smem + 32768);
    VMW(8);
    BAR();

#pragma unroll 1
    for (int j = 0; j < 6; ++j) {
        const int kt2 = 2 * j + 2, kt3 = 2 * j + 3;
        READ_B(0, 0); READ_B(0, 1); READ_A(0, 0);
        BAR(); LGKM0(); MFMA_Q(0, 0); BAR();
        BAR(); LGKM0(); MFMA_Q(0, 1); BAR();
        READ_A(0, 1);
        if (j < 5) STAGE_PAIR(gB0, gB1, kt2, smem + 16384);
        BAR(); LGKM0(); MFMA_Q(1, 0); BAR();
        if (j < 5) { STAGE_PAIR(gA0, gA1, kt2, smem); VMW(4); }
        else       { VMW(0); }
        BAR(); LGKM0(); MFMA_Q(1, 1); BAR();
        READ_B(1, 0); READ_B(1, 1); READ_A(1, 0);
        BAR(); LGKM0(); MFMA_Q(0, 0); BAR();
        BAR(); LGKM0(); MFMA_Q(0, 1); BAR();
        READ_A(1, 1);
        if (j < 5) STAGE_PAIR(gB0, gB1, kt3, smem + 32768 + 16384);
        BAR(); LGKM0(); MFMA_Q(1, 0); BAR();
        if (j < 5) { STAGE_PAIR(gA0, gA1, kt3, smem + 32768); VMW(4); }
        BAR(); LGKM0(); MFMA_Q(1, 1); BAR();
    }

    const int crow = lkg * 4;
#pragma unroll
    for (int n = 0; n < 4; ++n) {
        const int gc = col0 + wc * 64 + n * 16 + lr;
        const float bv = bias[gc];
#pragma unroll
        for (int m = 0; m < 8; ++m) {
            const size_t gr = (size_t)row0 + wr * 128 + m * 16 + crow;
#pragma unroll
            for (int r = 0; r < 4; ++r) {
                float v = acc[m][n][r] + bv;
                OUT[(gr + r) * EMB + gc] = (_Float16)(v > 0.f ? v : 0.f);
            }
        }
    }
#undef STAGE_PAIR
#undef READ_A
#undef READ_B
#undef MFMA_Q
}

// ---------- attention: 64 doc rows/block, QK with counted-vmcnt 4-phase ledger ----------
// Slots s0 @0, s1 @12288 hw (each: D 4096 | Q 8192). P[64][136] aliases after QK.
// LEDGER (6 loads/stage; every wave's VMW precedes a barrier that precedes any read):
//   prologue: STAGE(0->s0), STAGE(1->s1)  [12 outstanding]
//   P1: if j>0 STAGE(2j+1->s1); VMW(6) -> retires stage_s0(2j) [12 out -> 6];
//       BAR; read s0 kk0; LGKM0; 8 MFMA; BAR
//   P2: read s0 kk1; LGKM0; 8 MFMA; BAR          (s0 reads sealed here)
//   P3: if j<5 STAGE(2j+2->s0) else nothing; VMW(6)/VMW(0) -> retires stage_s1(2j+1);
//       BAR; read s1 kk0; LGKM0; 8 MFMA; BAR
//   P4: read s1 kk1; LGKM0; 8 MFMA; BAR          (s1 reads sealed; next P1 stages s1)
//   In-flight window per stage = 2 compute phases; never drains to 0 mid-loop.
__global__ __launch_bounds__(256) void attn64_kernel(
    const _Float16* __restrict__ Do, const _Float16* __restrict__ Qo,
    const _Float16* __restrict__ VT, float* __restrict__ OUT) {
    __shared__ __align__(16) _Float16 smem[24576];
    const int tid = threadIdx.x, wave = tid >> 6, lane = tid & 63;
    const int lr = lane & 15, lkg = lane >> 4;

    const int l = blockIdx.x;
    const int x = l & 7, i = l >> 3;
    const int b = x * 4 + (i >> 4), dblk = i & 15;

    const _Float16* gd = Do + ((size_t)b * LD + dblk * 64) * EMB;
    const _Float16* gq = Qo + (size_t)b * LQ * EMB;

#define STAGE6(kt, base) do { \
    stage_d64(gd + (kt) * 64, (base), tid); \
    stage_tile(gq + (kt) * 64, (base) + 4096, tid); } while (0)

    f32x4 s[8];
#pragma unroll
    for (int n = 0; n < 8; ++n) s[n] = (f32x4){0.f, 0.f, 0.f, 0.f};

    f16x8 am, bq[8];
#define READ_KK(base, kk) do { \
    const _Float16* sD_ = (base); const _Float16* sQ_ = (base) + 4096; \
    const int ch_ = (kk) * 4 + lkg; \
    am = *(const f16x8*)(sD_ + SWZ(wave * 16 + lr, ch_)); \
    _Pragma("unroll") for (int n_ = 0; n_ < 8; ++n_) \
        bq[n_] = *(const f16x8*)(sQ_ + SWZ(n_ * 16 + lr, ch_)); } while (0)
#define MFMA8() do { __builtin_amdgcn_s_setprio(1); \
    _Pragma("unroll") for (int n_ = 0; n_ < 8; ++n_) \
        s[n_] = __builtin_amdgcn_mfma_f32_16x16x32_f16(am, bq[n_], s[n_], 0, 0, 0); \
    __builtin_amdgcn_s_setprio(0); } while (0)

    // prologue
    STAGE6(0, smem);
    STAGE6(1, smem + 12288);

#pragma unroll
    for (int j = 0; j < 6; ++j) {
        // P1
        if (j > 0) STAGE6(2 * j + 1, smem + 12288);
        VMW(6);
        BAR();
        READ_KK(smem, 0);
        LGKM0(); MFMA8();
        BAR();
        // P2
        READ_KK(smem, 1);
        LGKM0(); MFMA8();
        BAR();
        // P3
        if (j < 5) { STAGE6(2 * j + 2, smem); VMW(6); }
        else       { VMW(0); }
        BAR();
        READ_KK(smem + 12288, 0);
        LGKM0(); MFMA8();
        BAR();
        // P4
        READ_KK(smem + 12288, 1);
        LGKM0(); MFMA8();
        BAR();
    }
#undef STAGE6
#undef READ_KK
#undef MFMA8
    __syncthreads();  // seal before P aliases slot memory

    _Float16 (*P)[136] = (_Float16 (*)[136])smem;
    const int crow = lkg * 4;
#pragma unroll
    for (int r = 0; r < 4; ++r) {
        float mx = -1e30f;
#pragma unroll
        for (int n = 0; n < 8; ++n) mx = fmaxf(mx, s[n][r]);
#pragma unroll
        for (int off = 1; off < 16; off <<= 1) mx = fmaxf(mx, __shfl_xor(mx, off));
        float p[8], sum = 0.f;
#pragma unroll
        for (int n = 0; n < 8; ++n) { p[n] = __expf(s[n][r] - mx); sum += p[n]; }
#pragma unroll
        for (int off = 1; off < 16; off <<= 1) sum += __shfl_xor(sum, off);
        const float inv = 1.f / sum;
        const int row = wave * 16 + crow + r;
#pragma unroll
        for (int n = 0; n < 8; ++n) P[row][n * 16 + lr] = (_Float16)(p[n] * inv);
    }
    __syncthreads();

    const _Float16* vtb = VT + (size_t)b * EMB * LQ;
    const size_t dbase = (size_t)b * LD + dblk * 64 + wave * 16 + crow;
#pragma unroll 1
    for (int nc = 0; nc < 6; ++nc) {
        f32x4 o[8];
#pragma unroll
        for (int t = 0; t < 8; ++t) o[t] = (f32x4){0.f, 0.f, 0.f, 0.f};
#pragma unroll
        for (int ks = 0; ks < 4; ++ks) {
            const f16x8 pa = *(const f16x8*)(&P[wave * 16 + lr][ks * 32 + lkg * 8]);
#pragma unroll
            for (int t = 0; t < 8; ++t) {
                const f16x8 bv = *(const f16x8*)(vtb + (size_t)(nc * 128 + t * 16 + lr) * LQ
                                                 + ks * 32 + lkg * 8);
                o[t] = __builtin_amdgcn_mfma_f32_16x16x32_f16(pa, bv, o[t], 0, 0, 0);
            }
        }
#pragma unroll
        for (int t = 0; t < 8; ++t) {
            const int e = nc * 128 + t * 16 + lr;
#pragma unroll
            for (int r = 0; r < 4; ++r)
                OUT[(dbase + r) * EMB + e] = o[t][r];
        }
    }
}

extern "C" void kernel_launch(void* const* d_in, const int* in_sizes, int n_in,
                              void* d_out, int out_size, void* d_ws, size_t ws_size,
                              hipStream_t stream) {
    const float* doc   = (const float*)d_in[0];   // [32,1024,768]
    const float* query = (const float*)d_in[1];   // [32,128,768]
    const float* W     = (const float*)d_in[2];   // [768,768]
    const float* bias  = (const float*)d_in[3];   // [768]
    float* out = (float*)d_out;                   // [32,1024,768] f32

    const size_t nW  = (size_t)EMB * EMB;        // 589824
    const size_t nVT = (size_t)NB * EMB * LQ;    // 3145728
    const size_t nDo = (size_t)NB * LD * EMB;    // 25165824
    const size_t nQo = (size_t)NB * LQ * EMB;    // 3145728
    const size_t need = (nW + nVT + nDo + nQo) * sizeof(_Float16);  // ~64.1 MB
    if (ws_size < need) return;

    _Float16* W16 = (_Float16*)d_ws;
    _Float16* VT  = W16 + nW;
    _Float16* Do  = VT + nVT;    // Do || Qo contiguous: merged proj output
    _Float16* Qo  = Do + nDo;

    // f16 doc||query contiguous in d_out (dead until attn overwrites it)
    _Float16* doc16 = (_Float16*)d_out;
    _Float16* q16   = doc16 + nDo;

    cvt_all_kernel<<<DOCB + QB + WB, 256, 0, stream>>>(doc, query, W, doc16, q16, W16);
    make_vt_kernel<<<dim3(2, 12, NB), 256, 0, stream>>>(query, VT);

    // merged projection: M = 36864 -> 144 rowblks x 3 colblks = 432 blocks, 128KB LDS
    hipFuncSetAttribute(reinterpret_cast<const void*>(&proj8_kernel),
                        hipFuncAttributeMaxDynamicSharedMemorySize, 131072);
    proj8_kernel<<<dim3(144 * 3), 512, 131072, stream>>>(doc16, W16, bias, Do);

    attn64_kernel<<<dim3(NB * 16), 256, 0, stream>>>(Do, Qo, VT, out);
}